// Round 21
// baseline (68.258 us; speedup 1.0000x reference)
//
#include <hip/hip_runtime.h>

#define D    128
#define SP   136   // u16 row stride for bf16 LDS planes (272B, 16B-aligned)
#define FS   132   // fp32 row stride for LDS output staging (528B, 16B-aligned)
#define NC   2     // column-tiles per wave (4 waves x 2 ct = 8 ct)
#define CAP  64    // per-node bucket capacity (Poisson(16): P(deg>64) ~ 1e-24)

typedef __attribute__((ext_vector_type(8))) short bf16x8;
typedef __attribute__((ext_vector_type(4))) float f32x4;
typedef unsigned short u16;

__device__ __forceinline__ float sigmoidf(float v) { return 1.0f / (1.0f + __expf(-v)); }

__device__ __forceinline__ u16 f2bf(float x) {
    union { float f; unsigned u; } c; c.f = x;
    return (u16)((c.u + 0x7fffu + ((c.u >> 16) & 1u)) >> 16);
}
__device__ __forceinline__ float bflo(unsigned u) {
    union { unsigned v; float f; } c; c.v = u << 16; return c.f;
}
__device__ __forceinline__ float bfhi(unsigned u) {
    union { unsigned v; float f; } c; c.v = u & 0xffff0000u; return c.f;
}
__device__ __forceinline__ void acc8(float* a, uint4 q) {
    a[0] += bflo(q.x); a[1] += bfhi(q.x);
    a[2] += bflo(q.y); a[3] += bfhi(q.y);
    a[4] += bflo(q.z); a[5] += bfhi(q.z);
    a[6] += bflo(q.w); a[7] += bfhi(q.w);
}

// Preload one layer's weight fragments (this wave's NC column-tiles) into regs.
__device__ __forceinline__ void preload_w(const short* __restrict__ WbM,
                                          int lane, int ctbase, bf16x8 w[4 * NC])
{
    #pragma unroll
    for (int ks = 0; ks < 4; ++ks)
        #pragma unroll
        for (int c = 0; c < NC; ++c)
            w[ks * NC + c] = *reinterpret_cast<const bf16x8*>(
                WbM + ((ctbase + c) * 4 + ks) * 512 + lane * 8);
}

// ---------------------------------------------------------------------------
// 32x128 @ 128x(NC*16) partial layer, single bf16 product, weights in regs.
// A-frag: row = rt*16+(lane&15), k = ks*32+(lane>>4)*8+e  (verified r3)
// ---------------------------------------------------------------------------
__device__ __forceinline__ void layer32_reg(
    const u16* __restrict__ plane, const bf16x8 w[4 * NC],
    int lane, f32x4 acc[NC][2])
{
    #pragma unroll
    for (int ks = 0; ks < 4; ++ks) {
        bf16x8 a[2];
        #pragma unroll
        for (int rt = 0; rt < 2; ++rt)
            a[rt] = *reinterpret_cast<const bf16x8*>(
                plane + (rt * 16 + (lane & 15)) * SP + ks * 32 + (lane >> 4) * 8);
        #pragma unroll
        for (int c = 0; c < NC; ++c) {
            const bf16x8 b = w[ks * NC + c];
            #pragma unroll
            for (int rt = 0; rt < 2; ++rt)
                acc[c][rt] = __builtin_amdgcn_mfma_f32_16x16x32_bf16(a[rt], b, acc[c][rt], 0, 0, 0);
        }
    }
}

// relu(acc+b1) -> bf16 dst plane.  C/D: row = rt*16+(lane>>4)*4+rr, col = ct*16+(lane&15)
__device__ __forceinline__ void store_t32(
    const f32x4 acc[NC][2], const float b1v[NC],
    u16* __restrict__ dst, int lane, int ctbase)
{
    #pragma unroll
    for (int c = 0; c < NC; ++c)
        #pragma unroll
        for (int rt = 0; rt < 2; ++rt)
            #pragma unroll
            for (int rr = 0; rr < 4; ++rr)
                dst[(rt * 16 + (lane >> 4) * 4 + rr) * SP + (ctbase + c) * 16 + (lane & 15)] =
                    f2bf(fmaxf(acc[c][rt][rr] + b1v[c], 0.f));
}

// Stage 32 fp32 rows -> bf16 plane (4 float4/thread, coalesced).
__device__ __forceinline__ void stage32(
    const float* __restrict__ src, int base, int N, int tid, u16* __restrict__ plane)
{
    #pragma unroll
    for (int it = 0; it < 4; ++it) {
        const int idx = it * 256 + tid;
        const int row = idx >> 5, c4 = (idx & 31) << 2;
        int node = base + row; if (node >= N) node = N - 1;
        const float4 v = *reinterpret_cast<const float4*>(&src[(size_t)node * D + c4]);
        ushort4 s;
        s.x = f2bf(v.x); s.y = f2bf(v.y); s.z = f2bf(v.z); s.w = f2bf(v.w);
        *reinterpret_cast<ushort4*>(&plane[row * SP + c4]) = s;
    }
}

// ---------------------------------------------------------------------------
// Node-MLP tail: P1 holds ready bf16 input plane (callers barrier before).
// Weights preloaded by caller: wA (layer1), wB (W2n).
// ---------------------------------------------------------------------------
__device__ __forceinline__ void mlp_tail(
    const bf16x8 wA[4 * NC], const bf16x8 wB[4 * NC],
    const float* __restrict__ b1n, const float* __restrict__ b2n,
    const float* __restrict__ h, float* __restrict__ out_h,
    int r, int base, int N,
    u16* __restrict__ P1, u16* __restrict__ P2, u16* __restrict__ smem)
{
    const int tid = threadIdx.x, lane = tid & 63, w = tid >> 6;
    const int ctbase = w * NC;

    float b1v[NC], b2v[NC];
    #pragma unroll
    for (int c = 0; c < NC; ++c) {
        const int j = (ctbase + c) * 16 + (lane & 15);
        b1v[c] = b1n[j]; b2v[c] = b2n[j];
    }

    f32x4 acc[NC][2];
    #pragma unroll
    for (int c = 0; c < NC; ++c)
        #pragma unroll
        for (int rt = 0; rt < 2; ++rt) acc[c][rt] = (f32x4){0.f, 0.f, 0.f, 0.f};
    layer32_reg(P1, wA, lane, acc);
    store_t32(acc, b1v, P2, lane, ctbase);
    __syncthreads();

    f32x4 o[NC][2];
    #pragma unroll
    for (int c = 0; c < NC; ++c)
        #pragma unroll
        for (int rt = 0; rt < 2; ++rt) o[c][rt] = (f32x4){0.f, 0.f, 0.f, 0.f};
    layer32_reg(P2, wB, lane, o);
    __syncthreads();   // all plane reads done -> smem reusable as fp32

    float* fs = reinterpret_cast<float*>(smem);
    #pragma unroll
    for (int c = 0; c < NC; ++c)
        #pragma unroll
        for (int rt = 0; rt < 2; ++rt)
            #pragma unroll
            for (int rr = 0; rr < 4; ++rr)
                fs[(rt * 16 + (lane >> 4) * 4 + rr) * FS + (ctbase + c) * 16 + (lane & 15)] =
                    o[c][rt][rr] + b2v[c];
    __syncthreads();

    const int nl = tid >> 3, cg = tid & 7;
    const int node = base + nl;
    if (node < N) {
        #pragma unroll
        for (int k = 0; k < 4; ++k) {
            float4 ov = *reinterpret_cast<const float4*>(&fs[nl * FS + cg * 16 + k * 4]);
            const float4 hv = *reinterpret_cast<const float4*>(&h[(size_t)node * D + cg * 16 + k * 4]);
            ov.x += hv.x; ov.y += hv.y; ov.z += hv.z; ov.w += hv.w;
            *reinterpret_cast<float4*>(&out_h[((size_t)node * 3 + r) * D + cg * 16 + k * 4]) = ov;
        }
    }
}

// ---------------------------------------------------------------------------
// K1: zero cnt || weight repack (compact bf16) || x passthrough.
// Wb matrices: 0=W1e[:D] 1=W1e[D:] 2=W2e 3=W1n[:D] 4=W1n[D:] 5=W2n
// ---------------------------------------------------------------------------
__global__ __launch_bounds__(256) void zero_repack_x_kernel(
    int* __restrict__ cnt, int N, int ZB,
    const float* __restrict__ W1e, const float* __restrict__ W2e,
    const float* __restrict__ W1n, const float* __restrict__ W2n,
    short* __restrict__ Wb,
    const float* __restrict__ x, float* __restrict__ out_x)
{
    const int RB = 48;
    if (blockIdx.x < (unsigned)ZB) {
        const int i = blockIdx.x * 256 + threadIdx.x;
        if (i < N) cnt[i] = 0;
        return;
    }
    if (blockIdx.x >= (unsigned)(ZB + RB)) {   // x copy
        const int i4 = ((blockIdx.x - ZB - RB) * 256 + threadIdx.x) * 4;
        const int total = N * 3;
        if (i4 + 3 < total) {
            *reinterpret_cast<float4*>(&out_x[i4]) =
                *reinterpret_cast<const float4*>(&x[i4]);
        } else {
            for (int k = i4; k < total && k < i4 + 4; ++k) out_x[k] = x[k];
        }
        return;
    }
    const int gid = (blockIdx.x - ZB) * 256 + threadIdx.x;
    if (gid >= 6 * 8 * 4 * 64) return;
    const int lane = gid & 63;
    int t = gid >> 6;
    const int ks = t & 3; t >>= 2;
    const int ct = t & 7;
    const int m  = t >> 3;
    const float* src;
    switch (m) {
        case 0: src = W1e;             break;
        case 1: src = W1e + 128 * 128; break;
        case 2: src = W2e;             break;
        case 3: src = W1n;             break;
        case 4: src = W1n + 128 * 128; break;
        default: src = W2n;            break;
    }
    const int j  = ct * 16 + (lane & 15);
    const int k0 = ks * 32 + (lane >> 4) * 8;
    bf16x8 hi;
    #pragma unroll
    for (int e = 0; e < 8; ++e) hi[e] = (short)f2bf(src[(size_t)(k0 + e) * 128 + j]);
    *reinterpret_cast<bf16x8*>(Wb + (size_t)m * 16384 + (ct * 4 + ks) * 512 + lane * 8) = hi;
}

// ---------------------------------------------------------------------------
// K2: Q1-pre (QB blocks) || r2 MLP (MB blocks) || edge scatter (SB, last).
// ---------------------------------------------------------------------------
__global__ __launch_bounds__(256, 4) void k2_pre_r2_scatter(
    const float* __restrict__ h, const short* __restrict__ Wb,
    const float* __restrict__ b1e, const float* __restrict__ b2e,
    const float* __restrict__ Wg,  const float* __restrict__ bg,
    const float* __restrict__ b1n, const float* __restrict__ b2n,
    u16* __restrict__ Q1b, float* __restrict__ out_h,
    int N, int QB, int MB,
    const int* __restrict__ ei, int E, int* __restrict__ cnt, int* __restrict__ bucket)
{
    __shared__ __align__(16) u16 smem[2 * 32 * SP];
    __shared__ float red_s[4][32];
    u16* P1 = smem;
    u16* P2 = smem + 32 * SP;

    const unsigned bid = blockIdx.x;
    const int tid = threadIdx.x, lane = tid & 63, w = tid >> 6;
    const int ctbase = w * NC;

    if (bid >= (unsigned)(QB + MB)) {   // ---- scatter ----
        const int e = (bid - QB - MB) * 256 + tid;
        if (e < E) {
            const int s = ei[e];
            const int d = ei[E + e];
            const int slot = atomicAdd(&cnt[d], 1);
            if (slot < CAP) bucket[(size_t)d * CAP + slot] = s;
        }
        return;
    }

    if (bid >= (unsigned)QB) {          // ---- r2: node MLP on h ----
        const int base = (bid - QB) * 32;
        bf16x8 wA[4 * NC], wB[4 * NC];
        preload_w(Wb + (size_t)4 * 16384, lane, ctbase, wA);
        preload_w(Wb + (size_t)5 * 16384, lane, ctbase, wB);
        stage32(h, base, N, tid, P1);
        __syncthreads();
        mlp_tail(wA, wB, b1n, b2n, h, out_h, 2, base, N, P1, P2, smem);
        return;
    }

    // ---- Q1-pre: P1(n) = relu(h@W1e[D:]+b1e)@W2e+b2e; Q1b = bf16(P1*g1) ----
    const int base = bid * 32;
    bf16x8 wA[4 * NC], wB[4 * NC];
    preload_w(Wb + (size_t)1 * 16384, lane, ctbase, wA);
    preload_w(Wb + (size_t)2 * 16384, lane, ctbase, wB);
    stage32(h, base, N, tid, P1);
    __syncthreads();

    float b1v[NC], b2v[NC], wgv[NC];
    #pragma unroll
    for (int c = 0; c < NC; ++c) {
        const int j = (ctbase + c) * 16 + (lane & 15);
        b1v[c] = b1e[j]; b2v[c] = b2e[j]; wgv[c] = Wg[j];
    }
    const float bgv = bg[0];

    f32x4 acc[NC][2];
    #pragma unroll
    for (int c = 0; c < NC; ++c)
        #pragma unroll
        for (int rt = 0; rt < 2; ++rt) acc[c][rt] = (f32x4){0.f, 0.f, 0.f, 0.f};
    layer32_reg(P1, wA, lane, acc);
    store_t32(acc, b1v, P2, lane, ctbase);
    __syncthreads();

    f32x4 p[NC][2];
    #pragma unroll
    for (int c = 0; c < NC; ++c)
        #pragma unroll
        for (int rt = 0; rt < 2; ++rt) p[c][rt] = (f32x4){0.f, 0.f, 0.f, 0.f};
    layer32_reg(P2, wB, lane, p);

    #pragma unroll
    for (int rt = 0; rt < 2; ++rt)
        #pragma unroll
        for (int rr = 0; rr < 4; ++rr) {
            float part = 0.f;
            #pragma unroll
            for (int c = 0; c < NC; ++c) part += (p[c][rt][rr] + b2v[c]) * wgv[c];
            #pragma unroll
            for (int m = 1; m <= 8; m <<= 1) part += __shfl_xor(part, m, 64);
            if ((lane & 15) == 0)
                red_s[w][rt * 16 + (lane >> 4) * 4 + rr] = part;
        }
    __syncthreads();

    #pragma unroll
    for (int rt = 0; rt < 2; ++rt)
        #pragma unroll
        for (int rr = 0; rr < 4; ++rr) {
            const int row = rt * 16 + (lane >> 4) * 4 + rr;
            const float g = sigmoidf(red_s[0][row] + red_s[1][row] +
                                     red_s[2][row] + red_s[3][row] + bgv);
            #pragma unroll
            for (int c = 0; c < NC; ++c)
                P1[row * SP + (ctbase + c) * 16 + (lane & 15)] =
                    f2bf((p[c][rt][rr] + b2v[c]) * g);
        }
    __syncthreads();

    const int nl = tid >> 3, cg = tid & 7;
    const int node = base + nl;
    if (node < N) {
        const uint4 v0 = *reinterpret_cast<const uint4*>(&P1[nl * SP + cg * 16]);
        const uint4 v1 = *reinterpret_cast<const uint4*>(&P1[nl * SP + cg * 16 + 8]);
        *reinterpret_cast<uint4*>(&Q1b[(size_t)node * D + cg * 16])     = v0;
        *reinterpret_cast<uint4*>(&Q1b[(size_t)node * D + cg * 16 + 8]) = v1;
    }
}

// ---------------------------------------------------------------------------
// K3: r1 gather-MLP (first RT blocks) || r0 fused edge+node MLP (rest).
// ---------------------------------------------------------------------------
__global__ __launch_bounds__(256, 4) void k3_r1_r0(
    const float* __restrict__ h,  const u16* __restrict__ Q1b,
    const short* __restrict__ Wb,
    const float* __restrict__ b1e, const float* __restrict__ b2e,
    const float* __restrict__ Wg,  const float* __restrict__ bg,
    const float* __restrict__ b1n, const float* __restrict__ b2n,
    const int* __restrict__ cnt,  const int* __restrict__ bucket,
    float* __restrict__ out_h, int N, int RT)
{
    __shared__ __align__(16) u16 smem[2 * 32 * SP];
    __shared__ float red_s[4][32];
    u16* P1 = smem;
    u16* P2 = smem + 32 * SP;

    const int tid = threadIdx.x, lane = tid & 63, w = tid >> 6;
    const int ctbase = w * NC;

    if (blockIdx.x < (unsigned)RT) {
        // ---- r1: gather sum of Q1b rows -> P1 -> node MLP ----
        // weight preload overlaps the gather's L2 latency
        bf16x8 wA[4 * NC], wB[4 * NC];
        preload_w(Wb + (size_t)3 * 16384, lane, ctbase, wA);
        preload_w(Wb + (size_t)5 * 16384, lane, ctbase, wB);

        const int base = blockIdx.x * 32;
        const int nl = tid >> 3, cg = tid & 7;   // 8 threads/node, 16 ch each
        int node = base + nl; if (node >= N) node = N - 1;
        int deg = cnt[node]; if (deg > CAP) deg = CAP;
        const int* __restrict__ bk = bucket + (size_t)node * CAP;
        const u16* __restrict__ Qc = Q1b + cg * 16;
        float a[16] = {0.f,0.f,0.f,0.f,0.f,0.f,0.f,0.f,0.f,0.f,0.f,0.f,0.f,0.f,0.f,0.f};
        int i = 0;
        for (; i + 1 < deg; i += 2) {
            const int s0 = bk[i], s1 = bk[i + 1];
            const uint4 qa0 = *reinterpret_cast<const uint4*>(Qc + (size_t)s0 * D);
            const uint4 qb0 = *reinterpret_cast<const uint4*>(Qc + (size_t)s0 * D + 8);
            const uint4 qa1 = *reinterpret_cast<const uint4*>(Qc + (size_t)s1 * D);
            const uint4 qb1 = *reinterpret_cast<const uint4*>(Qc + (size_t)s1 * D + 8);
            acc8(a, qa0); acc8(a + 8, qb0);
            acc8(a, qa1); acc8(a + 8, qb1);
        }
        if (i < deg) {
            const int s = bk[i];
            const uint4 qa = *reinterpret_cast<const uint4*>(Qc + (size_t)s * D);
            const uint4 qb = *reinterpret_cast<const uint4*>(Qc + (size_t)s * D + 8);
            acc8(a, qa); acc8(a + 8, qb);
        }
        #pragma unroll
        for (int k4 = 0; k4 < 4; ++k4) {
            ushort4 s4;
            s4.x = f2bf(a[k4 * 4 + 0]); s4.y = f2bf(a[k4 * 4 + 1]);
            s4.z = f2bf(a[k4 * 4 + 2]); s4.w = f2bf(a[k4 * 4 + 3]);
            *reinterpret_cast<ushort4*>(&P1[nl * SP + cg * 16 + k4 * 4]) = s4;
        }
        __syncthreads();
        mlp_tail(wA, wB, b1n, b2n, h, out_h, 1, base, N, P1, P2, smem);
        return;
    }

    // ---- r0 fused: P0 = edge-MLP(h); in0 = cnt*P0*g0; node MLP -> row 0 ----
    const int base = (blockIdx.x - RT) * 32;
    bf16x8 wA[4 * NC], wB[4 * NC];
    preload_w(Wb, lane, ctbase, wA);                       // W1e[:D]
    preload_w(Wb + (size_t)2 * 16384, lane, ctbase, wB);   // W2e
    stage32(h, base, N, tid, P1);
    __syncthreads();

    float b1v[NC], b2v[NC], wgv[NC];
    #pragma unroll
    for (int c = 0; c < NC; ++c) {
        const int j = (ctbase + c) * 16 + (lane & 15);
        b1v[c] = b1e[j]; b2v[c] = b2e[j]; wgv[c] = Wg[j];
    }
    const float bgv = bg[0];

    f32x4 acc[NC][2];
    #pragma unroll
    for (int c = 0; c < NC; ++c)
        #pragma unroll
        for (int rt = 0; rt < 2; ++rt) acc[c][rt] = (f32x4){0.f, 0.f, 0.f, 0.f};
    layer32_reg(P1, wA, lane, acc);
    store_t32(acc, b1v, P2, lane, ctbase);
    __syncthreads();

    f32x4 p[NC][2];
    #pragma unroll
    for (int c = 0; c < NC; ++c)
        #pragma unroll
        for (int rt = 0; rt < 2; ++rt) p[c][rt] = (f32x4){0.f, 0.f, 0.f, 0.f};
    layer32_reg(P2, wB, lane, p);

    // reload weight regs with the node-MLP pair; loads overlap gate + barrier
    preload_w(Wb + (size_t)3 * 16384, lane, ctbase, wA);   // W1n[:D]
    preload_w(Wb + (size_t)5 * 16384, lane, ctbase, wB);   // W2n

    #pragma unroll
    for (int rt = 0; rt < 2; ++rt)
        #pragma unroll
        for (int rr = 0; rr < 4; ++rr) {
            float part = 0.f;
            #pragma unroll
            for (int c = 0; c < NC; ++c) part += (p[c][rt][rr] + b2v[c]) * wgv[c];
            #pragma unroll
            for (int m = 1; m <= 8; m <<= 1) part += __shfl_xor(part, m, 64);
            if ((lane & 15) == 0)
                red_s[w][rt * 16 + (lane >> 4) * 4 + rr] = part;
        }
    __syncthreads();

    #pragma unroll
    for (int rt = 0; rt < 2; ++rt)
        #pragma unroll
        for (int rr = 0; rr < 4; ++rr) {
            const int row = rt * 16 + (lane >> 4) * 4 + rr;
            const float g = sigmoidf(red_s[0][row] + red_s[1][row] +
                                     red_s[2][row] + red_s[3][row] + bgv);
            int node2 = base + row; if (node2 >= N) node2 = N - 1;
            const float cv = (float)cnt[node2];
            #pragma unroll
            for (int c = 0; c < NC; ++c)
                P1[row * SP + (ctbase + c) * 16 + (lane & 15)] =
                    f2bf(cv * (p[c][rt][rr] + b2v[c]) * g);
        }
    __syncthreads();
    mlp_tail(wA, wB, b1n, b2n, h, out_h, 0, base, N, P1, P2, smem);
}

// ---------------------------------------------------------------------------
extern "C" void kernel_launch(void* const* d_in, const int* in_sizes, int n_in,
                              void* d_out, int out_size, void* d_ws, size_t ws_size,
                              hipStream_t stream)
{
    const float* h   = (const float*)d_in[0];
    const float* x   = (const float*)d_in[1];
    const int*   ei  = (const int*)d_in[2];
    const float* W1e = (const float*)d_in[3];
    const float* b1e = (const float*)d_in[4];
    const float* W2e = (const float*)d_in[5];
    const float* b2e = (const float*)d_in[6];
    const float* Wg  = (const float*)d_in[7];
    const float* bg  = (const float*)d_in[8];
    const float* W1n = (const float*)d_in[9];
    const float* b1n = (const float*)d_in[10];
    const float* W2n = (const float*)d_in[11];
    const float* b2n = (const float*)d_in[12];

    const int N = in_sizes[0] / D;
    const int E = in_sizes[2] / 2;

    // workspace: Q1b(bf16) | Wb | cnt | bucket
    u16*   Q1b    = (u16*)d_ws;
    short* Wb     = (short*)(Q1b + (size_t)N * D);
    int*   cnt    = (int*)(Wb + 6 * 16384);
    int*   bucket = cnt + N;

    float* out_h = (float*)d_out;                 // [N,3,D]
    float* out_x = out_h + (size_t)N * 3 * D;     // [N,3]

    const int nt = (N + 31) / 32;
    const int ZB = (N + 255) / 256;               // zero blocks
    const int RB = 48;                            // repack blocks
    const int XB = (N * 3 + 1023) / 1024;         // x-copy blocks (float4)
    const int QB = nt;                            // Q1-pre blocks
    const int MB = nt;                            // r2 blocks
    const int SB = (E + 255) / 256;               // scatter blocks

    zero_repack_x_kernel<<<ZB + RB + XB, 256, 0, stream>>>(cnt, N, ZB,
                                                           W1e, W2e, W1n, W2n, Wb, x, out_x);
    k2_pre_r2_scatter<<<QB + MB + SB, 256, 0, stream>>>(h, Wb, b1e, b2e, Wg, bg,
                                                        b1n, b2n, Q1b, out_h,
                                                        N, QB, MB, ei, E, cnt, bucket);
    k3_r1_r0<<<nt * 2, 256, 0, stream>>>(h, Q1b, Wb, b1e, b2e, Wg, bg,
                                         b1n, b2n, cnt, bucket, out_h, N, nt);
}

// Round 22
// 55.936 us; speedup vs baseline: 1.2203x; 1.2203x over previous
//
#include <hip/hip_runtime.h>

#define D    128
#define SP   136   // u16 row stride for bf16 LDS planes (272B, 16B-aligned)
#define FS   132   // fp32 row stride for LDS output staging (528B, 16B-aligned)
#define NC   2     // column-tiles per wave (4 waves x 2 ct = 8 ct)
#define CAP  64    // per-node bucket capacity (Poisson(16): P(deg>64) ~ 1e-24)

typedef __attribute__((ext_vector_type(8))) short bf16x8;
typedef __attribute__((ext_vector_type(4))) float f32x4;
typedef unsigned short u16;

__device__ __forceinline__ float sigmoidf(float v) { return 1.0f / (1.0f + __expf(-v)); }

__device__ __forceinline__ u16 f2bf(float x) {
    union { float f; unsigned u; } c; c.f = x;
    return (u16)((c.u + 0x7fffu + ((c.u >> 16) & 1u)) >> 16);
}
__device__ __forceinline__ float bflo(unsigned u) {
    union { unsigned v; float f; } c; c.v = u << 16; return c.f;
}
__device__ __forceinline__ float bfhi(unsigned u) {
    union { unsigned v; float f; } c; c.v = u & 0xffff0000u; return c.f;
}
__device__ __forceinline__ void acc8(float* a, uint4 q) {
    a[0] += bflo(q.x); a[1] += bfhi(q.x);
    a[2] += bflo(q.y); a[3] += bfhi(q.y);
    a[4] += bflo(q.z); a[5] += bfhi(q.z);
    a[6] += bflo(q.w); a[7] += bfhi(q.w);
}

// ---------------------------------------------------------------------------
// 32x128 @ 128x(NC*16) partial layer, single bf16 product, inline L2 weights.
// A-frag: row = rt*16+(lane&15), k = ks*32+(lane>>4)*8+e  (verified r3)
// ---------------------------------------------------------------------------
__device__ __forceinline__ void layer32(
    const u16* __restrict__ plane, const short* __restrict__ WbM,
    int lane, int ctbase, f32x4 acc[NC][2])
{
    #pragma unroll
    for (int ks = 0; ks < 4; ++ks) {
        bf16x8 a[2];
        #pragma unroll
        for (int rt = 0; rt < 2; ++rt)
            a[rt] = *reinterpret_cast<const bf16x8*>(
                plane + (rt * 16 + (lane & 15)) * SP + ks * 32 + (lane >> 4) * 8);
        #pragma unroll
        for (int c = 0; c < NC; ++c) {
            const bf16x8 b = *reinterpret_cast<const bf16x8*>(
                WbM + ((ctbase + c) * 4 + ks) * 512 + lane * 8);
            #pragma unroll
            for (int rt = 0; rt < 2; ++rt)
                acc[c][rt] = __builtin_amdgcn_mfma_f32_16x16x32_bf16(a[rt], b, acc[c][rt], 0, 0, 0);
        }
    }
}

// relu(acc+b1) -> bf16 dst plane.  C/D: row = rt*16+(lane>>4)*4+rr, col = ct*16+(lane&15)
__device__ __forceinline__ void store_t32(
    const f32x4 acc[NC][2], const float b1v[NC],
    u16* __restrict__ dst, int lane, int ctbase)
{
    #pragma unroll
    for (int c = 0; c < NC; ++c)
        #pragma unroll
        for (int rt = 0; rt < 2; ++rt)
            #pragma unroll
            for (int rr = 0; rr < 4; ++rr)
                dst[(rt * 16 + (lane >> 4) * 4 + rr) * SP + (ctbase + c) * 16 + (lane & 15)] =
                    f2bf(fmaxf(acc[c][rt][rr] + b1v[c], 0.f));
}

// Stage 32 fp32 rows -> bf16 plane (4 float4/thread, coalesced).
__device__ __forceinline__ void stage32(
    const float* __restrict__ src, int base, int N, int tid, u16* __restrict__ plane)
{
    #pragma unroll
    for (int it = 0; it < 4; ++it) {
        const int idx = it * 256 + tid;
        const int row = idx >> 5, c4 = (idx & 31) << 2;
        int node = base + row; if (node >= N) node = N - 1;
        const float4 v = *reinterpret_cast<const float4*>(&src[(size_t)node * D + c4]);
        ushort4 s;
        s.x = f2bf(v.x); s.y = f2bf(v.y); s.z = f2bf(v.z); s.w = f2bf(v.w);
        *reinterpret_cast<ushort4*>(&plane[row * SP + c4]) = s;
    }
}

// ---------------------------------------------------------------------------
// Node-MLP tail: P1 holds ready bf16 input plane (callers barrier before).
// layer(mA) -> relu -> layer(m5) -> +b2n + h residual -> out_h row r.
// ---------------------------------------------------------------------------
__device__ __forceinline__ void mlp_tail(
    const short* __restrict__ Wb, int mA,
    const float* __restrict__ b1n, const float* __restrict__ b2n,
    const float* __restrict__ h, float* __restrict__ out_h,
    int r, int base, int N,
    u16* __restrict__ P1, u16* __restrict__ P2, u16* __restrict__ smem)
{
    const int tid = threadIdx.x, lane = tid & 63, w = tid >> 6;
    const int ctbase = w * NC;

    float b1v[NC], b2v[NC];
    #pragma unroll
    for (int c = 0; c < NC; ++c) {
        const int j = (ctbase + c) * 16 + (lane & 15);
        b1v[c] = b1n[j]; b2v[c] = b2n[j];
    }

    f32x4 acc[NC][2];
    #pragma unroll
    for (int c = 0; c < NC; ++c)
        #pragma unroll
        for (int rt = 0; rt < 2; ++rt) acc[c][rt] = (f32x4){0.f, 0.f, 0.f, 0.f};
    layer32(P1, Wb + (size_t)mA * 16384, lane, ctbase, acc);
    store_t32(acc, b1v, P2, lane, ctbase);
    __syncthreads();

    f32x4 o[NC][2];
    #pragma unroll
    for (int c = 0; c < NC; ++c)
        #pragma unroll
        for (int rt = 0; rt < 2; ++rt) o[c][rt] = (f32x4){0.f, 0.f, 0.f, 0.f};
    layer32(P2, Wb + (size_t)5 * 16384, lane, ctbase, o);
    __syncthreads();   // all plane reads done -> smem reusable as fp32

    float* fs = reinterpret_cast<float*>(smem);
    #pragma unroll
    for (int c = 0; c < NC; ++c)
        #pragma unroll
        for (int rt = 0; rt < 2; ++rt)
            #pragma unroll
            for (int rr = 0; rr < 4; ++rr)
                fs[(rt * 16 + (lane >> 4) * 4 + rr) * FS + (ctbase + c) * 16 + (lane & 15)] =
                    o[c][rt][rr] + b2v[c];
    __syncthreads();

    const int nl = tid >> 3, cg = tid & 7;
    const int node = base + nl;
    if (node < N) {
        #pragma unroll
        for (int k = 0; k < 4; ++k) {
            float4 ov = *reinterpret_cast<const float4*>(&fs[nl * FS + cg * 16 + k * 4]);
            const float4 hv = *reinterpret_cast<const float4*>(&h[(size_t)node * D + cg * 16 + k * 4]);
            ov.x += hv.x; ov.y += hv.y; ov.z += hv.z; ov.w += hv.w;
            *reinterpret_cast<float4*>(&out_h[((size_t)node * 3 + r) * D + cg * 16 + k * 4]) = ov;
        }
    }
}

// ---------------------------------------------------------------------------
// K1: zero cnt || weight repack (compact bf16) || x passthrough.
// Wb matrices: 0=W1e[:D] 1=W1e[D:] 2=W2e 3=W1n[:D] 4=W1n[D:] 5=W2n
// ---------------------------------------------------------------------------
__global__ __launch_bounds__(256) void zero_repack_x_kernel(
    int* __restrict__ cnt, int N, int ZB,
    const float* __restrict__ W1e, const float* __restrict__ W2e,
    const float* __restrict__ W1n, const float* __restrict__ W2n,
    short* __restrict__ Wb,
    const float* __restrict__ x, float* __restrict__ out_x)
{
    const int RB = 48;
    if (blockIdx.x < (unsigned)ZB) {
        const int i = blockIdx.x * 256 + threadIdx.x;
        if (i < N) cnt[i] = 0;
        return;
    }
    if (blockIdx.x >= (unsigned)(ZB + RB)) {   // x copy
        const int i4 = ((blockIdx.x - ZB - RB) * 256 + threadIdx.x) * 4;
        const int total = N * 3;
        if (i4 + 3 < total) {
            *reinterpret_cast<float4*>(&out_x[i4]) =
                *reinterpret_cast<const float4*>(&x[i4]);
        } else {
            for (int k = i4; k < total && k < i4 + 4; ++k) out_x[k] = x[k];
        }
        return;
    }
    const int gid = (blockIdx.x - ZB) * 256 + threadIdx.x;
    if (gid >= 6 * 8 * 4 * 64) return;
    const int lane = gid & 63;
    int t = gid >> 6;
    const int ks = t & 3; t >>= 2;
    const int ct = t & 7;
    const int m  = t >> 3;
    const float* src;
    switch (m) {
        case 0: src = W1e;             break;
        case 1: src = W1e + 128 * 128; break;
        case 2: src = W2e;             break;
        case 3: src = W1n;             break;
        case 4: src = W1n + 128 * 128; break;
        default: src = W2n;            break;
    }
    const int j  = ct * 16 + (lane & 15);
    const int k0 = ks * 32 + (lane >> 4) * 8;
    bf16x8 hi;
    #pragma unroll
    for (int e = 0; e < 8; ++e) hi[e] = (short)f2bf(src[(size_t)(k0 + e) * 128 + j]);
    *reinterpret_cast<bf16x8*>(Wb + (size_t)m * 16384 + (ct * 4 + ks) * 512 + lane * 8) = hi;
}

// ---------------------------------------------------------------------------
// K2: Q1-pre (QB blocks) || r2 MLP (MB blocks) || edge scatter (SB, last).
// ---------------------------------------------------------------------------
__global__ __launch_bounds__(256, 4) void k2_pre_r2_scatter(
    const float* __restrict__ h, const short* __restrict__ Wb,
    const float* __restrict__ b1e, const float* __restrict__ b2e,
    const float* __restrict__ Wg,  const float* __restrict__ bg,
    const float* __restrict__ b1n, const float* __restrict__ b2n,
    u16* __restrict__ Q1b, float* __restrict__ out_h,
    int N, int QB, int MB,
    const int* __restrict__ ei, int E, int* __restrict__ cnt, int* __restrict__ bucket)
{
    __shared__ __align__(16) u16 smem[2 * 32 * SP];
    __shared__ float red_s[4][32];
    u16* P1 = smem;
    u16* P2 = smem + 32 * SP;

    const unsigned bid = blockIdx.x;
    const int tid = threadIdx.x, lane = tid & 63, w = tid >> 6;

    if (bid >= (unsigned)(QB + MB)) {   // ---- scatter ----
        const int e = (bid - QB - MB) * 256 + tid;
        if (e < E) {
            const int s = ei[e];
            const int d = ei[E + e];
            const int slot = atomicAdd(&cnt[d], 1);
            if (slot < CAP) bucket[(size_t)d * CAP + slot] = s;
        }
        return;
    }

    if (bid >= (unsigned)QB) {          // ---- r2: node MLP on h ----
        const int base = (bid - QB) * 32;
        stage32(h, base, N, tid, P1);
        __syncthreads();
        mlp_tail(Wb, 4, b1n, b2n, h, out_h, 2, base, N, P1, P2, smem);
        return;
    }

    // ---- Q1-pre: P1(n) = relu(h@W1e[D:]+b1e)@W2e+b2e; Q1b = bf16(P1*g1) ----
    const int base = bid * 32;
    const int ctbase = w * NC;
    stage32(h, base, N, tid, P1);
    __syncthreads();

    float b1v[NC], b2v[NC], wgv[NC];
    #pragma unroll
    for (int c = 0; c < NC; ++c) {
        const int j = (ctbase + c) * 16 + (lane & 15);
        b1v[c] = b1e[j]; b2v[c] = b2e[j]; wgv[c] = Wg[j];
    }
    const float bgv = bg[0];

    f32x4 acc[NC][2];
    #pragma unroll
    for (int c = 0; c < NC; ++c)
        #pragma unroll
        for (int rt = 0; rt < 2; ++rt) acc[c][rt] = (f32x4){0.f, 0.f, 0.f, 0.f};
    layer32(P1, Wb + (size_t)1 * 16384, lane, ctbase, acc);
    store_t32(acc, b1v, P2, lane, ctbase);
    __syncthreads();

    f32x4 p[NC][2];
    #pragma unroll
    for (int c = 0; c < NC; ++c)
        #pragma unroll
        for (int rt = 0; rt < 2; ++rt) p[c][rt] = (f32x4){0.f, 0.f, 0.f, 0.f};
    layer32(P2, Wb + (size_t)2 * 16384, lane, ctbase, p);

    #pragma unroll
    for (int rt = 0; rt < 2; ++rt)
        #pragma unroll
        for (int rr = 0; rr < 4; ++rr) {
            float part = 0.f;
            #pragma unroll
            for (int c = 0; c < NC; ++c) part += (p[c][rt][rr] + b2v[c]) * wgv[c];
            #pragma unroll
            for (int m = 1; m <= 8; m <<= 1) part += __shfl_xor(part, m, 64);
            if ((lane & 15) == 0)
                red_s[w][rt * 16 + (lane >> 4) * 4 + rr] = part;
        }
    __syncthreads();

    #pragma unroll
    for (int rt = 0; rt < 2; ++rt)
        #pragma unroll
        for (int rr = 0; rr < 4; ++rr) {
            const int row = rt * 16 + (lane >> 4) * 4 + rr;
            const float g = sigmoidf(red_s[0][row] + red_s[1][row] +
                                     red_s[2][row] + red_s[3][row] + bgv);
            #pragma unroll
            for (int c = 0; c < NC; ++c)
                P1[row * SP + (ctbase + c) * 16 + (lane & 15)] =
                    f2bf((p[c][rt][rr] + b2v[c]) * g);
        }
    __syncthreads();

    const int nl = tid >> 3, cg = tid & 7;
    const int node = base + nl;
    if (node < N) {
        const uint4 v0 = *reinterpret_cast<const uint4*>(&P1[nl * SP + cg * 16]);
        const uint4 v1 = *reinterpret_cast<const uint4*>(&P1[nl * SP + cg * 16 + 8]);
        *reinterpret_cast<uint4*>(&Q1b[(size_t)node * D + cg * 16])     = v0;
        *reinterpret_cast<uint4*>(&Q1b[(size_t)node * D + cg * 16 + 8]) = v1;
    }
}

// ---------------------------------------------------------------------------
// K3: r1 gather-MLP (first RT blocks) || r0 fused edge+node MLP (rest).
// ---------------------------------------------------------------------------
__global__ __launch_bounds__(256, 4) void k3_r1_r0(
    const float* __restrict__ h,  const u16* __restrict__ Q1b,
    const short* __restrict__ Wb,
    const float* __restrict__ b1e, const float* __restrict__ b2e,
    const float* __restrict__ Wg,  const float* __restrict__ bg,
    const float* __restrict__ b1n, const float* __restrict__ b2n,
    const int* __restrict__ cnt,  const int* __restrict__ bucket,
    float* __restrict__ out_h, int N, int RT)
{
    __shared__ __align__(16) u16 smem[2 * 32 * SP];
    __shared__ float red_s[4][32];
    u16* P1 = smem;
    u16* P2 = smem + 32 * SP;

    const int tid = threadIdx.x, lane = tid & 63, w = tid >> 6;
    const int ctbase = w * NC;

    if (blockIdx.x < (unsigned)RT) {
        // ---- r1: gather sum of Q1b rows -> P1 -> node MLP ----
        const int base = blockIdx.x * 32;
        const int nl = tid >> 3, cg = tid & 7;   // 8 threads/node, 16 ch each
        int node = base + nl; if (node >= N) node = N - 1;
        int deg = cnt[node]; if (deg > CAP) deg = CAP;
        const int* __restrict__ bk = bucket + (size_t)node * CAP;
        const u16* __restrict__ Qc = Q1b + cg * 16;
        float a[16] = {0.f,0.f,0.f,0.f,0.f,0.f,0.f,0.f,0.f,0.f,0.f,0.f,0.f,0.f,0.f,0.f};
        int i = 0;
        for (; i + 1 < deg; i += 2) {
            const int s0 = bk[i], s1 = bk[i + 1];
            const uint4 qa0 = *reinterpret_cast<const uint4*>(Qc + (size_t)s0 * D);
            const uint4 qb0 = *reinterpret_cast<const uint4*>(Qc + (size_t)s0 * D + 8);
            const uint4 qa1 = *reinterpret_cast<const uint4*>(Qc + (size_t)s1 * D);
            const uint4 qb1 = *reinterpret_cast<const uint4*>(Qc + (size_t)s1 * D + 8);
            acc8(a, qa0); acc8(a + 8, qb0);
            acc8(a, qa1); acc8(a + 8, qb1);
        }
        if (i < deg) {
            const int s = bk[i];
            const uint4 qa = *reinterpret_cast<const uint4*>(Qc + (size_t)s * D);
            const uint4 qb = *reinterpret_cast<const uint4*>(Qc + (size_t)s * D + 8);
            acc8(a, qa); acc8(a + 8, qb);
        }
        #pragma unroll
        for (int k4 = 0; k4 < 4; ++k4) {
            ushort4 s4;
            s4.x = f2bf(a[k4 * 4 + 0]); s4.y = f2bf(a[k4 * 4 + 1]);
            s4.z = f2bf(a[k4 * 4 + 2]); s4.w = f2bf(a[k4 * 4 + 3]);
            *reinterpret_cast<ushort4*>(&P1[nl * SP + cg * 16 + k4 * 4]) = s4;
        }
        __syncthreads();
        mlp_tail(Wb, 3, b1n, b2n, h, out_h, 1, base, N, P1, P2, smem);
        return;
    }

    // ---- r0 fused: P0 = edge-MLP(h); in0 = cnt*P0*g0; node MLP -> row 0 ----
    const int base = (blockIdx.x - RT) * 32;
    stage32(h, base, N, tid, P1);
    __syncthreads();

    float b1v[NC], b2v[NC], wgv[NC];
    #pragma unroll
    for (int c = 0; c < NC; ++c) {
        const int j = (ctbase + c) * 16 + (lane & 15);
        b1v[c] = b1e[j]; b2v[c] = b2e[j]; wgv[c] = Wg[j];
    }
    const float bgv = bg[0];

    f32x4 acc[NC][2];
    #pragma unroll
    for (int c = 0; c < NC; ++c)
        #pragma unroll
        for (int rt = 0; rt < 2; ++rt) acc[c][rt] = (f32x4){0.f, 0.f, 0.f, 0.f};
    layer32(P1, Wb, lane, ctbase, acc);                     // W1e[:D]
    store_t32(acc, b1v, P2, lane, ctbase);
    __syncthreads();

    f32x4 p[NC][2];
    #pragma unroll
    for (int c = 0; c < NC; ++c)
        #pragma unroll
        for (int rt = 0; rt < 2; ++rt) p[c][rt] = (f32x4){0.f, 0.f, 0.f, 0.f};
    layer32(P2, Wb + (size_t)2 * 16384, lane, ctbase, p);   // W2e

    #pragma unroll
    for (int rt = 0; rt < 2; ++rt)
        #pragma unroll
        for (int rr = 0; rr < 4; ++rr) {
            float part = 0.f;
            #pragma unroll
            for (int c = 0; c < NC; ++c) part += (p[c][rt][rr] + b2v[c]) * wgv[c];
            #pragma unroll
            for (int m = 1; m <= 8; m <<= 1) part += __shfl_xor(part, m, 64);
            if ((lane & 15) == 0)
                red_s[w][rt * 16 + (lane >> 4) * 4 + rr] = part;
        }
    __syncthreads();

    #pragma unroll
    for (int rt = 0; rt < 2; ++rt)
        #pragma unroll
        for (int rr = 0; rr < 4; ++rr) {
            const int row = rt * 16 + (lane >> 4) * 4 + rr;
            const float g = sigmoidf(red_s[0][row] + red_s[1][row] +
                                     red_s[2][row] + red_s[3][row] + bgv);
            int node2 = base + row; if (node2 >= N) node2 = N - 1;
            const float cv = (float)cnt[node2];
            #pragma unroll
            for (int c = 0; c < NC; ++c)
                P1[row * SP + (ctbase + c) * 16 + (lane & 15)] =
                    f2bf(cv * (p[c][rt][rr] + b2v[c]) * g);
        }
    __syncthreads();
    mlp_tail(Wb, 3, b1n, b2n, h, out_h, 0, base, N, P1, P2, smem);
}

// ---------------------------------------------------------------------------
extern "C" void kernel_launch(void* const* d_in, const int* in_sizes, int n_in,
                              void* d_out, int out_size, void* d_ws, size_t ws_size,
                              hipStream_t stream)
{
    const float* h   = (const float*)d_in[0];
    const float* x   = (const float*)d_in[1];
    const int*   ei  = (const int*)d_in[2];
    const float* W1e = (const float*)d_in[3];
    const float* b1e = (const float*)d_in[4];
    const float* W2e = (const float*)d_in[5];
    const float* b2e = (const float*)d_in[6];
    const float* Wg  = (const float*)d_in[7];
    const float* bg  = (const float*)d_in[8];
    const float* W1n = (const float*)d_in[9];
    const float* b1n = (const float*)d_in[10];
    const float* W2n = (const float*)d_in[11];
    const float* b2n = (const float*)d_in[12];

    const int N = in_sizes[0] / D;
    const int E = in_sizes[2] / 2;

    // workspace: Q1b(bf16) | Wb | cnt | bucket
    u16*   Q1b    = (u16*)d_ws;
    short* Wb     = (short*)(Q1b + (size_t)N * D);
    int*   cnt    = (int*)(Wb + 6 * 16384);
    int*   bucket = cnt + N;

    float* out_h = (float*)d_out;                 // [N,3,D]
    float* out_x = out_h + (size_t)N * 3 * D;     // [N,3]

    const int nt = (N + 31) / 32;
    const int ZB = (N + 255) / 256;               // zero blocks
    const int RB = 48;                            // repack blocks
    const int XB = (N * 3 + 1023) / 1024;         // x-copy blocks (float4)
    const int QB = nt;                            // Q1-pre blocks
    const int MB = nt;                            // r2 blocks
    const int SB = (E + 255) / 256;               // scatter blocks

    zero_repack_x_kernel<<<ZB + RB + XB, 256, 0, stream>>>(cnt, N, ZB,
                                                           W1e, W2e, W1n, W2n, Wb, x, out_x);
    k2_pre_r2_scatter<<<QB + MB + SB, 256, 0, stream>>>(h, Wb, b1e, b2e, Wg, bg,
                                                        b1n, b2n, Q1b, out_h,
                                                        N, QB, MB, ei, E, cnt, bucket);
    k3_r1_r0<<<nt * 2, 256, 0, stream>>>(h, Q1b, Wb, b1e, b2e, Wg, bg,
                                         b1n, b2n, cnt, bucket, out_h, N, nt);
}